// Round 2
// baseline (734.040 us; speedup 1.0000x reference)
//
#include <hip/hip_runtime.h>
#include <hip/hip_bf16.h>

// Social-LSTM on MI355X. All inputs/outputs fp32 (reference dtypes).
//
// Reorder: te = relu( (sum_{(p,g) in nz(grid[n])} U[p,g,:]) + b_soc )
// with U[p,g,e] = sum_h h[p,h] * W_soc[e, g*128+h]  (per-frame GEMM).

#define TT   12
#define NN   1000
#define RNNW 128
#define EMBW 64
#define GGW  16
#define OUTD 5
#define UCW  (GGW*EMBW)   // 1024
#define AKW  256          // [ie(64) | te(64) | h(128)]
#define NGATE 512
#define GROW (NN*GGW)     // 16000 floats per (t,n) grid row

__device__ __forceinline__ float sigmf(float x) { return 1.f / (1.f + __expf(-x)); }

// ---- init: copy fp32 h0/c0 -> mutable ws state --------------------------
__global__ void k_init(const float* __restrict__ h0, const float* __restrict__ c0,
                       float* __restrict__ h, float* __restrict__ c) {
    int i = blockIdx.x * 256 + threadIdx.x;
    if (i < NN * RNNW) { h[i] = h0[i]; c[i] = c0[i]; }
}

// ---- U[p, g*64+e] = sum_k h[p,k] * W_soc[e, g*128+k] -------------------
// grid (32, 16): 32 p-tiles of 32, blockIdx.y = g. 256 threads.
__global__ __launch_bounds__(256) void k_U(const float* __restrict__ h,
                                           const float* __restrict__ Wsoc,
                                           float* __restrict__ U) {
    __shared__ float sA[32][RNNW];       // h tile; compute reads are wave-uniform (broadcast)
    __shared__ float sB[64][RNNW + 1];   // +1 pad: conflict-free sB[tx][k] reads
    const int tid = threadIdx.x;
    const int p0 = blockIdx.x * 32;
    const int g  = blockIdx.y;
    {   // load h tile (float4)
        int r = tid >> 3, c0_ = (tid & 7) * 16;
        int p = p0 + r;
        const float4 z = {0.f, 0.f, 0.f, 0.f};
        #pragma unroll
        for (int q = 0; q < 4; q++) {
            float4 v = z;
            if (p < NN) v = *(const float4*)(h + (size_t)p * RNNW + c0_ + q * 4);
            *(float4*)(&sA[r][c0_ + q * 4]) = v;
        }
    }
    {   // load W_soc slice: rows e=0..63, cols g*128..g*128+127 (vec loads, scalar LDS stores)
        int e = tid >> 2, c0_ = (tid & 3) * 32;
        const float* src = Wsoc + (size_t)e * (GGW * RNNW) + g * RNNW + c0_;
        #pragma unroll
        for (int q = 0; q < 8; q++) {
            float4 v = *(const float4*)(src + q * 4);
            sB[e][c0_ + q * 4 + 0] = v.x;
            sB[e][c0_ + q * 4 + 1] = v.y;
            sB[e][c0_ + q * 4 + 2] = v.z;
            sB[e][c0_ + q * 4 + 3] = v.w;
        }
    }
    __syncthreads();
    const int tx = tid & 63, ty = tid >> 6;
    float acc[8];
    #pragma unroll
    for (int i = 0; i < 8; i++) acc[i] = 0.f;
    for (int k = 0; k < RNNW; k++) {
        float b = sB[tx][k];
        #pragma unroll
        for (int i = 0; i < 8; i++) acc[i] += sA[ty + 4 * i][k] * b;
    }
    #pragma unroll
    for (int i = 0; i < 8; i++) {
        int p = p0 + ty + 4 * i;
        if (p < NN) U[(size_t)p * UCW + g * EMBW + tx] = acc[i];
    }
}

// ---- pooling + input embedding: one block (512 thr) per pedestrian n ----
// scan grid[t,n,:,:] (16000 fp32), ballot-compact nonzeros, gather U rows.
__global__ __launch_bounds__(512) void k_pool(const unsigned int* __restrict__ grids,
                                              const float* __restrict__ x_in,
                                              const float* __restrict__ U,
                                              const float* __restrict__ h,
                                              const float* __restrict__ W_in,
                                              const float* __restrict__ b_in,
                                              const float* __restrict__ b_soc,
                                              float* __restrict__ A, int t) {
    const int n = blockIdx.x;
    const int tid = threadIdx.x;
    const int lane = tid & 63, wave = tid >> 6;          // 8 waves
    const unsigned int* gp = grids + ((size_t)t * NN + n) * (size_t)GROW;
    float acc = 0.f;   // accumulator for e = lane
    for (int it = 0; it < 8; ++it) {
        int base = (it * 8 + wave) * 256;                // wave-uniform
        if (base >= GROW) break;
        int f0 = base + lane * 4;
        uint4 v = {0u, 0u, 0u, 0u};
        if (f0 < GROW) v = *(const uint4*)(gp + f0);     // GROW % 4 == 0 -> safe
        unsigned int va[4] = {v.x, v.y, v.z, v.w};
        #pragma unroll
        for (int sub = 0; sub < 4; ++sub) {
            unsigned long long m = __ballot(va[sub] != 0u);
            while (m) {
                int b = __builtin_ctzll(m); m &= m - 1;
                int f = base + b * 4 + sub;
                int p = f >> 4, g = f & 15;
                acc += U[(size_t)p * UCW + g * EMBW + lane];
            }
        }
    }
    __shared__ float sAcc[8][64];
    sAcc[wave][lane] = acc;
    __syncthreads();
    if (tid < 64) {
        float s = 0.f;
        #pragma unroll
        for (int w = 0; w < 8; w++) s += sAcc[w][tid];
        float te = fmaxf(s + b_soc[tid], 0.f);
        float x0 = x_in[((size_t)t * NN + n) * 2 + 0];
        float x1 = x_in[((size_t)t * NN + n) * 2 + 1];
        float ie = fmaxf(W_in[tid * 2 + 0] * x0 + W_in[tid * 2 + 1] * x1 + b_in[tid], 0.f);
        A[(size_t)n * AKW + tid] = ie;
        A[(size_t)n * AKW + EMBW + tid] = te;
    } else if (tid >= 128 && tid < 256) {
        int k = tid - 128;
        A[(size_t)n * AKW + 128 + k] = h[(size_t)n * RNNW + k];
    }
}

// ---- gates[n,j] = sum_k A[n,k]*Wcat[j,k] + b_ih[j]+b_hh[j] -------------
// grid (32, 8): 32 n-tiles of 32, 8 j-tiles of 64. K=256 in 2 chunks.
__global__ __launch_bounds__(256) void k_gates(const float* __restrict__ A,
                                               const float* __restrict__ W_ih,
                                               const float* __restrict__ W_hh,
                                               const float* __restrict__ b_ih,
                                               const float* __restrict__ b_hh,
                                               float* __restrict__ gates) {
    __shared__ float sA[32][128];
    __shared__ float sB[64][129];
    const int tid = threadIdx.x;
    const int n0 = blockIdx.x * 32;
    const int j0 = blockIdx.y * 64;
    const int tx = tid & 63, ty = tid >> 6;
    float acc[8];
    #pragma unroll
    for (int i = 0; i < 8; i++) acc[i] = 0.f;
    for (int kk = 0; kk < 2; ++kk) {
        __syncthreads();
        {   // A chunk
            int r = tid >> 3, c0_ = (tid & 7) * 16;
            int n = n0 + r;
            const float4 z = {0.f, 0.f, 0.f, 0.f};
            #pragma unroll
            for (int q = 0; q < 4; q++) {
                float4 v = z;
                if (n < NN) v = *(const float4*)(A + (size_t)n * AKW + kk * 128 + c0_ + q * 4);
                *(float4*)(&sA[r][c0_ + q * 4]) = v;
            }
        }
        {   // weight chunk: W_ih (kk=0) or W_hh (kk=1), rows j0..j0+63
            int e = tid >> 2, c0_ = (tid & 3) * 32;
            const float* W = kk ? W_hh : W_ih;
            const float* src = W + (size_t)(j0 + e) * 128 + c0_;
            #pragma unroll
            for (int q = 0; q < 8; q++) {
                float4 v = *(const float4*)(src + q * 4);
                sB[e][c0_ + q * 4 + 0] = v.x;
                sB[e][c0_ + q * 4 + 1] = v.y;
                sB[e][c0_ + q * 4 + 2] = v.z;
                sB[e][c0_ + q * 4 + 3] = v.w;
            }
        }
        __syncthreads();
        for (int k = 0; k < 128; k++) {
            float b = sB[tx][k];
            #pragma unroll
            for (int i = 0; i < 8; i++) acc[i] += sA[ty + 4 * i][k] * b;
        }
    }
    float bias = b_ih[j0 + tx] + b_hh[j0 + tx];
    #pragma unroll
    for (int i = 0; i < 8; i++) {
        int n = n0 + ty + 4 * i;
        if (n < NN) gates[(size_t)n * NGATE + j0 + tx] = acc[i] + bias;
    }
}

// ---- LSTM elementwise + out projection ---------------------------------
// block = 2 pedestrians x 128 threads
__global__ __launch_bounds__(256) void k_lstm(const float* __restrict__ gates,
                                              float* __restrict__ h, float* __restrict__ c,
                                              const float* __restrict__ W_out,
                                              const float* __restrict__ b_out,
                                              float* __restrict__ out, int t) {
    __shared__ float sh[2][128];
    int tid = threadIdx.x;
    int local = tid >> 7;
    int r = tid & 127;
    int n = blockIdx.x * 2 + local;
    float hn = 0.f;
    if (n < NN) {
        const float* gr = gates + (size_t)n * NGATE;
        float gi = gr[r], gf = gr[128 + r], gg = gr[256 + r], go = gr[384 + r];
        float cn = sigmf(gf) * c[(size_t)n * RNNW + r] + sigmf(gi) * tanhf(gg);
        hn = sigmf(go) * tanhf(cn);
        c[(size_t)n * RNNW + r] = cn;
        h[(size_t)n * RNNW + r] = hn;
    }
    sh[local][r] = hn;
    __syncthreads();
    if (n < NN && r < OUTD) {
        float s = b_out[r];
        const float* wr = W_out + r * RNNW;
        for (int k = 0; k < RNNW; k++) s += sh[local][k] * wr[k];
        out[((size_t)t * NN + n) * OUTD + r] = s;
    }
}

// ---- final: fp32 h,c -> tail of d_out ----------------------------------
__global__ void k_final(const float* __restrict__ h, const float* __restrict__ c,
                        float* __restrict__ out) {
    int i = blockIdx.x * 256 + threadIdx.x;
    if (i < NN * RNNW) {
        out[TT * NN * OUTD + i] = h[i];
        out[TT * NN * OUTD + NN * RNNW + i] = c[i];
    }
}

extern "C" void kernel_launch(void* const* d_in, const int* in_sizes, int n_in,
                              void* d_out, int out_size, void* d_ws, size_t ws_size,
                              hipStream_t stream) {
    const float* x_in        = (const float*)d_in[0];   // [T,N,2]
    const unsigned int* grd  = (const unsigned int*)d_in[1]; // [T,N,N,G] fp32 raw bits
    const float* h0          = (const float*)d_in[2];
    const float* c0          = (const float*)d_in[3];
    const float* W_in        = (const float*)d_in[4];   // [64,2]
    const float* b_in        = (const float*)d_in[5];
    const float* W_soc       = (const float*)d_in[6];   // [64,2048]
    const float* b_soc       = (const float*)d_in[7];
    const float* W_ih        = (const float*)d_in[8];   // [512,128]
    const float* W_hh        = (const float*)d_in[9];   // [512,128]
    const float* b_ih        = (const float*)d_in[10];
    const float* b_hh        = (const float*)d_in[11];
    const float* W_out       = (const float*)d_in[12];  // [5,128]
    const float* b_out       = (const float*)d_in[13];
    float* out = (float*)d_out;

    float* h     = (float*)d_ws;                 // 128000
    float* c     = h + NN * RNNW;                // 128000
    float* U     = c + NN * RNNW;                // 1,024,000
    float* A     = U + (size_t)NN * UCW;         // 256,000
    float* gates = A + (size_t)NN * AKW;         // 512,000   (total ~8.2 MB)

    hipLaunchKernelGGL(k_init, dim3(500), dim3(256), 0, stream, h0, c0, h, c);
    for (int t = 0; t < TT; ++t) {
        hipLaunchKernelGGL(k_U,     dim3(32, 16), dim3(256), 0, stream, h, W_soc, U);
        hipLaunchKernelGGL(k_pool,  dim3(NN),     dim3(512), 0, stream, grd, x_in, U, h, W_in, b_in, b_soc, A, t);
        hipLaunchKernelGGL(k_gates, dim3(32, 8),  dim3(256), 0, stream, A, W_ih, W_hh, b_ih, b_hh, gates);
        hipLaunchKernelGGL(k_lstm,  dim3(500),    dim3(256), 0, stream, gates, h, c, W_out, b_out, out, t);
    }
    hipLaunchKernelGGL(k_final, dim3(500), dim3(256), 0, stream, h, c, out);
}

// Round 3
// 664.206 us; speedup vs baseline: 1.1051x; 1.1051x over previous
//
#include <hip/hip_runtime.h>
#include <hip/hip_bf16.h>

// Social-LSTM on MI355X. fp32 I/O.
// te = relu( (sum_{(p,g) in nz(grid[n])} U[p,g,:]) + b_soc ),
// U = h @ W_soc_g per cell g  (register-tiled VALU GEMM, k-major LDS).

#define TT   12
#define NN   1000
#define RNNW 128
#define EMBW 64
#define GGW  16
#define OUTD 5
#define UCW  (GGW*EMBW)   // 1024
#define AKW  256          // [ie(64) | te(64) | h(128)]
#define NGATE 512
#define GROW (NN*GGW)     // 16000 floats per (t,n) grid row

__device__ __forceinline__ float sigmf(float x) { return 1.f / (1.f + __expf(-x)); }

// ---- prep: h/c init + weight transposes (once per launch) ---------------
// WsT[gk][e]  = W_soc[e][gk]           (2048 x 64)
// WcT[k][j]   = k<128 ? W_ih[j][k] : W_hh[j][k-128]   (256 x 512)
__global__ void k_prep(const float* __restrict__ h0, const float* __restrict__ c0,
                       const float* __restrict__ W_soc,
                       const float* __restrict__ W_ih, const float* __restrict__ W_hh,
                       float* __restrict__ h, float* __restrict__ c,
                       float* __restrict__ WsT, float* __restrict__ WcT) {
    int i = blockIdx.x * 256 + threadIdx.x;
    if (i < 131072) {                     // W_soc: read coalesced, write scattered
        int e = i >> 11, gk = i & 2047;
        WsT[gk * 64 + e] = W_soc[i];
    } else if (i < 196608) {
        int i2 = i - 131072;              // W_ih [512][128]
        int j = i2 >> 7, k = i2 & 127;
        WcT[k * 512 + j] = W_ih[i2];
    } else if (i < 262144) {
        int i3 = i - 196608;              // W_hh
        int j = i3 >> 7, k = i3 & 127;
        WcT[(128 + k) * 512 + j] = W_hh[i3];
    } else if (i < 262144 + NN * RNNW) {
        int i4 = i - 262144; h[i4] = h0[i4];
    } else if (i < 262144 + 2 * NN * RNNW) {
        int i5 = i - 262144 - NN * RNNW; c[i5] = c0[i5];
    }
}

// ---- U[p, g*64+e] = sum_k h[p,k] * WsT[g*128+k][e] ---------------------
// grid (16,16): 16 p-tiles of 64, blockIdx.y = g. 256 thr, thread = 4x4.
__global__ __launch_bounds__(256) void k_U(const float* __restrict__ h,
                                           const float* __restrict__ WsT,
                                           float* __restrict__ U) {
    __shared__ float sAT[RNNW][64];   // k-major h tile
    __shared__ float sBT[RNNW][64];   // k-major W tile
    const int tid = threadIdx.x;
    const int p0 = blockIdx.x * 64;
    const int g  = blockIdx.y;
    {   // stage sAT: transpose h[p0+pp][k] -> sAT[k][pp]
        int pp = tid >> 2, kq = (tid & 3) * 4;
        int p = p0 + pp;
        #pragma unroll
        for (int pass = 0; pass < 8; ++pass) {
            int k0 = pass * 16 + kq;
            float4 v = {0.f, 0.f, 0.f, 0.f};
            if (p < NN) v = *(const float4*)(h + (size_t)p * RNNW + k0);
            sAT[k0 + 0][pp] = v.x; sAT[k0 + 1][pp] = v.y;
            sAT[k0 + 2][pp] = v.z; sAT[k0 + 3][pp] = v.w;
        }
    }
    {   // stage sBT: rows g*128..+127 of WsT, coalesced float4
        #pragma unroll
        for (int pass = 0; pass < 8; ++pass) {
            int f = pass * 256 + tid;          // f in 0..2047
            int k = f >> 4, e4 = (f & 15) * 4;
            float4 v = *(const float4*)(WsT + (size_t)(g * 128 + k) * 64 + e4);
            *(float4*)(&sBT[k][e4]) = v;
        }
    }
    __syncthreads();
    const int tx = tid & 15, ty = tid >> 4;    // 16 col-quads x 16 row-quads
    float acc[4][4];
    #pragma unroll
    for (int i = 0; i < 4; i++)
        #pragma unroll
        for (int j = 0; j < 4; j++) acc[i][j] = 0.f;
    #pragma unroll 4
    for (int k = 0; k < RNNW; ++k) {
        float4 a4 = *(const float4*)(&sAT[k][ty * 4]);
        float4 b4 = *(const float4*)(&sBT[k][tx * 4]);
        const float av[4] = {a4.x, a4.y, a4.z, a4.w};
        const float bv[4] = {b4.x, b4.y, b4.z, b4.w};
        #pragma unroll
        for (int i = 0; i < 4; i++)
            #pragma unroll
            for (int j = 0; j < 4; j++) acc[i][j] += av[i] * bv[j];
    }
    #pragma unroll
    for (int i = 0; i < 4; i++) {
        int p = p0 + ty * 4 + i;
        if (p < NN) {
            float4 v = {acc[i][0], acc[i][1], acc[i][2], acc[i][3]};
            *(float4*)(U + (size_t)p * UCW + g * EMBW + tx * 4) = v;
        }
    }
}

// ---- pooling + input embedding: one block (512 thr) per pedestrian n ----
__global__ __launch_bounds__(512) void k_pool(const unsigned int* __restrict__ grids,
                                              const float* __restrict__ x_in,
                                              const float* __restrict__ U,
                                              const float* __restrict__ h,
                                              const float* __restrict__ W_in,
                                              const float* __restrict__ b_in,
                                              const float* __restrict__ b_soc,
                                              float* __restrict__ A, int t) {
    const int n = blockIdx.x;
    const int tid = threadIdx.x;
    const int lane = tid & 63, wave = tid >> 6;          // 8 waves
    const unsigned int* gp = grids + ((size_t)t * NN + n) * (size_t)GROW;
    float acc = 0.f;   // accumulator for e = lane
    for (int it = 0; it < 8; ++it) {
        int base = (it * 8 + wave) * 256;                // wave-uniform
        if (base >= GROW) break;
        int f0 = base + lane * 4;
        uint4 v = {0u, 0u, 0u, 0u};
        if (f0 < GROW) v = *(const uint4*)(gp + f0);
        unsigned int va[4] = {v.x, v.y, v.z, v.w};
        #pragma unroll
        for (int sub = 0; sub < 4; ++sub) {
            unsigned long long m = __ballot(va[sub] != 0u);
            while (m) {
                int b = __builtin_ctzll(m); m &= m - 1;
                int f = base + b * 4 + sub;
                int p = f >> 4, g = f & 15;
                acc += U[(size_t)p * UCW + g * EMBW + lane];
            }
        }
    }
    __shared__ float sAcc[8][64];
    sAcc[wave][lane] = acc;
    __syncthreads();
    if (tid < 64) {
        float s = 0.f;
        #pragma unroll
        for (int w = 0; w < 8; w++) s += sAcc[w][tid];
        float te = fmaxf(s + b_soc[tid], 0.f);
        float x0 = x_in[((size_t)t * NN + n) * 2 + 0];
        float x1 = x_in[((size_t)t * NN + n) * 2 + 1];
        float ie = fmaxf(W_in[tid * 2 + 0] * x0 + W_in[tid * 2 + 1] * x1 + b_in[tid], 0.f);
        A[(size_t)n * AKW + tid] = ie;
        A[(size_t)n * AKW + EMBW + tid] = te;
    } else if (tid >= 128 && tid < 256) {
        int k = tid - 128;
        A[(size_t)n * AKW + 128 + k] = h[(size_t)n * RNNW + k];
    }
}

// ---- gates[n,j] = sum_k A[n,k]*WcT[k][j] + b_ih[j]+b_hh[j] -------------
// grid (32,8): 32 n-tiles of 32, 8 j-tiles of 64. 256 thr, thread = 2x4.
__global__ __launch_bounds__(256) void k_gates(const float* __restrict__ A,
                                               const float* __restrict__ WcT,
                                               const float* __restrict__ b_ih,
                                               const float* __restrict__ b_hh,
                                               float* __restrict__ gates) {
    __shared__ float sAT[128][32];
    __shared__ float sBT[128][64];
    const int tid = threadIdx.x;
    const int n0 = blockIdx.x * 32;
    const int j0 = blockIdx.y * 64;
    const int tx = tid & 15, ty = tid >> 4;
    float acc[2][4];
    #pragma unroll
    for (int i = 0; i < 2; i++)
        #pragma unroll
        for (int j = 0; j < 4; j++) acc[i][j] = 0.f;
    for (int kc = 0; kc < 2; ++kc) {
        __syncthreads();
        {   // stage sAT: transpose A[n0+nn][kc*128+k] -> sAT[k][nn]
            int nn = tid >> 3, kq = (tid & 7) * 4;
            int n = n0 + nn;
            #pragma unroll
            for (int pass = 0; pass < 4; ++pass) {
                int k0 = pass * 32 + kq;
                float4 v = {0.f, 0.f, 0.f, 0.f};
                if (n < NN) v = *(const float4*)(A + (size_t)n * AKW + kc * 128 + k0);
                sAT[k0 + 0][nn] = v.x; sAT[k0 + 1][nn] = v.y;
                sAT[k0 + 2][nn] = v.z; sAT[k0 + 3][nn] = v.w;
            }
        }
        {   // stage sBT: WcT rows kc*128..+127, cols j0..j0+63
            #pragma unroll
            for (int pass = 0; pass < 8; ++pass) {
                int f = pass * 256 + tid;      // 0..2047
                int k = f >> 4, e4 = (f & 15) * 4;
                float4 v = *(const float4*)(WcT + (size_t)(kc * 128 + k) * NGATE + j0 + e4);
                *(float4*)(&sBT[k][e4]) = v;
            }
        }
        __syncthreads();
        #pragma unroll 4
        for (int k = 0; k < 128; ++k) {
            float2 a2 = *(const float2*)(&sAT[k][ty * 2]);
            float4 b4 = *(const float4*)(&sBT[k][tx * 4]);
            const float av[2] = {a2.x, a2.y};
            const float bv[4] = {b4.x, b4.y, b4.z, b4.w};
            #pragma unroll
            for (int i = 0; i < 2; i++)
                #pragma unroll
                for (int j = 0; j < 4; j++) acc[i][j] += av[i] * bv[j];
        }
    }
    float4 bi = *(const float4*)(b_ih + j0 + tx * 4);
    float4 bh = *(const float4*)(b_hh + j0 + tx * 4);
    float bias[4] = {bi.x + bh.x, bi.y + bh.y, bi.z + bh.z, bi.w + bh.w};
    #pragma unroll
    for (int i = 0; i < 2; i++) {
        int n = n0 + ty * 2 + i;
        if (n < NN) {
            float4 v = {acc[i][0] + bias[0], acc[i][1] + bias[1],
                        acc[i][2] + bias[2], acc[i][3] + bias[3]};
            *(float4*)(gates + (size_t)n * NGATE + j0 + tx * 4) = v;
        }
    }
}

// ---- LSTM elementwise + out projection ---------------------------------
__global__ __launch_bounds__(256) void k_lstm(const float* __restrict__ gates,
                                              float* __restrict__ h, float* __restrict__ c,
                                              const float* __restrict__ W_out,
                                              const float* __restrict__ b_out,
                                              float* __restrict__ out, int t) {
    __shared__ float sh[2][128];
    int tid = threadIdx.x;
    int local = tid >> 7;
    int r = tid & 127;
    int n = blockIdx.x * 2 + local;
    float hn = 0.f;
    if (n < NN) {
        const float* gr = gates + (size_t)n * NGATE;
        float gi = gr[r], gf = gr[128 + r], gg = gr[256 + r], go = gr[384 + r];
        float cn = sigmf(gf) * c[(size_t)n * RNNW + r] + sigmf(gi) * tanhf(gg);
        hn = sigmf(go) * tanhf(cn);
        c[(size_t)n * RNNW + r] = cn;
        h[(size_t)n * RNNW + r] = hn;
    }
    sh[local][r] = hn;
    __syncthreads();
    if (n < NN && r < OUTD) {
        float s = b_out[r];
        const float* wr = W_out + r * RNNW;
        for (int k = 0; k < RNNW; k++) s += sh[local][k] * wr[k];
        out[((size_t)t * NN + n) * OUTD + r] = s;
    }
}

// ---- final: fp32 h,c -> tail of d_out ----------------------------------
__global__ void k_final(const float* __restrict__ h, const float* __restrict__ c,
                        float* __restrict__ out) {
    int i = blockIdx.x * 256 + threadIdx.x;
    if (i < NN * RNNW) {
        out[TT * NN * OUTD + i] = h[i];
        out[TT * NN * OUTD + NN * RNNW + i] = c[i];
    }
}

extern "C" void kernel_launch(void* const* d_in, const int* in_sizes, int n_in,
                              void* d_out, int out_size, void* d_ws, size_t ws_size,
                              hipStream_t stream) {
    const float* x_in        = (const float*)d_in[0];
    const unsigned int* grd  = (const unsigned int*)d_in[1];
    const float* h0          = (const float*)d_in[2];
    const float* c0          = (const float*)d_in[3];
    const float* W_in        = (const float*)d_in[4];
    const float* b_in        = (const float*)d_in[5];
    const float* W_soc       = (const float*)d_in[6];
    const float* b_soc       = (const float*)d_in[7];
    const float* W_ih        = (const float*)d_in[8];
    const float* W_hh        = (const float*)d_in[9];
    const float* b_ih        = (const float*)d_in[10];
    const float* b_hh        = (const float*)d_in[11];
    const float* W_out       = (const float*)d_in[12];
    const float* b_out       = (const float*)d_in[13];
    float* out = (float*)d_out;

    float* h     = (float*)d_ws;                 // 128000
    float* c     = h + NN * RNNW;                // 128000
    float* U     = c + NN * RNNW;                // 1,024,000
    float* A     = U + (size_t)NN * UCW;         // 256,000
    float* gates = A + (size_t)NN * AKW;         // 512,000
    float* WsT   = gates + (size_t)NN * NGATE;   // 131,072
    float* WcT   = WsT + 2048 * 64;              // 131,072  (total ~9.3 MB)

    hipLaunchKernelGGL(k_prep, dim3(2024), dim3(256), 0, stream,
                       h0, c0, W_soc, W_ih, W_hh, h, c, WsT, WcT);
    for (int t = 0; t < TT; ++t) {
        hipLaunchKernelGGL(k_U,     dim3(16, 16), dim3(256), 0, stream, h, WsT, U);
        hipLaunchKernelGGL(k_pool,  dim3(NN),     dim3(512), 0, stream, grd, x_in, U, h, W_in, b_in, b_soc, A, t);
        hipLaunchKernelGGL(k_gates, dim3(32, 8),  dim3(256), 0, stream, A, WcT, b_ih, b_hh, gates);
        hipLaunchKernelGGL(k_lstm,  dim3(500),    dim3(256), 0, stream, gates, h, c, W_out, b_out, out, t);
    }
    hipLaunchKernelGGL(k_final, dim3(500), dim3(256), 0, stream, h, c, out);
}